// Round 1
// baseline (276.150 us; speedup 1.0000x reference)
//
#include <hip/hip_runtime.h>
#include <hip/hip_bf16.h>

#define HID 1024
#define INTER 4096
#define NE 8
#define NTOK 2048
#define MAXROWS 5120   // 4096 pairs + 8*127 pad, rounded up

typedef __attribute__((ext_vector_type(8))) short short8v;
typedef __attribute__((ext_vector_type(4))) float f32x4;

__device__ __forceinline__ unsigned short f2bf(float f) {
  unsigned int u = __builtin_bit_cast(unsigned int, f);
  u = (u + 0x7FFFu + ((u >> 16) & 1u)) >> 16;
  return (unsigned short)u;
}
__device__ __forceinline__ float bf2f(unsigned short s) {
  unsigned int u = ((unsigned int)s) << 16;
  return __builtin_bit_cast(float, u);
}

typedef const __attribute__((address_space(1))) unsigned int* gas_t;
typedef __attribute__((address_space(3))) unsigned int* las_t;
__device__ __forceinline__ void gld16(const unsigned short* g, unsigned short* l) {
  __builtin_amdgcn_global_load_lds((gas_t)(const void*)g, (las_t)(void*)l, 16, 0, 0);
}

// ---------------- x fp32 -> bf16 (same layout) ----------------
__global__ __launch_bounds__(256) void convx_kernel(const float* __restrict__ in,
                                                    unsigned short* __restrict__ out) {
  size_t i = (size_t)blockIdx.x * 256 + threadIdx.x;
  f32x4 v = *(const f32x4*)&in[i * 4];
  uint2 r;
  r.x = (unsigned int)f2bf(v[0]) | ((unsigned int)f2bf(v[1]) << 16);
  r.y = (unsigned int)f2bf(v[2]) | ((unsigned int)f2bf(v[3]) << 16);
  *(uint2*)&out[i * 4] = r;
}

// ------------- transpose+convert: in [Z][R][C] f32 -> out [Z][C][R] bf16 -------------
__global__ __launch_bounds__(256) void tconv_kernel(const float* __restrict__ in,
                                                    unsigned short* __restrict__ out,
                                                    int R, int C) {
  __shared__ float t[64][65];
  const int z = blockIdx.z;
  const int r0 = blockIdx.y * 64, c0 = blockIdx.x * 64;
  const int tr = threadIdx.x / 16;
  const int tc = (threadIdx.x % 16) * 4;
  const float* ip = in + ((size_t)z * R + r0) * (size_t)C + c0;
#pragma unroll
  for (int p = 0; p < 4; ++p) {
    f32x4 v = *(const f32x4*)&ip[(size_t)(p * 16 + tr) * C + tc];
    t[p * 16 + tr][tc + 0] = v[0];
    t[p * 16 + tr][tc + 1] = v[1];
    t[p * 16 + tr][tc + 2] = v[2];
    t[p * 16 + tr][tc + 3] = v[3];
  }
  __syncthreads();
  unsigned short* op = out + ((size_t)z * C + c0) * (size_t)R + r0;
#pragma unroll
  for (int p = 0; p < 4; ++p) {
    int c = p * 16 + tr;
    unsigned int a0 = (unsigned int)f2bf(t[tc + 0][c]) | ((unsigned int)f2bf(t[tc + 1][c]) << 16);
    unsigned int a1 = (unsigned int)f2bf(t[tc + 2][c]) | ((unsigned int)f2bf(t[tc + 3][c]) << 16);
    uint2 val; val.x = a0; val.y = a1;
    *(uint2*)&op[(size_t)c * R + tc] = val;
  }
}

// ---------------- gating: logits -> top2 + softmax ----------------
__global__ __launch_bounds__(256) void gating_kernel(const float* __restrict__ x,
                                                     const float* __restrict__ wg,
                                                     int* __restrict__ tok_e,
                                                     float* __restrict__ tok_w) {
  const int t = blockIdx.x;
  float acc[NE];
#pragma unroll
  for (int e = 0; e < NE; ++e) acc[e] = 0.f;
  for (int k = threadIdx.x; k < HID; k += 256) {
    float xv = x[(size_t)t * HID + k];
#pragma unroll
    for (int e = 0; e < NE; ++e) acc[e] += xv * wg[e * HID + k];
  }
#pragma unroll
  for (int e = 0; e < NE; ++e) {
#pragma unroll
    for (int off = 32; off >= 1; off >>= 1) acc[e] += __shfl_xor(acc[e], off, 64);
  }
  __shared__ float red[4][NE];
  const int wave = threadIdx.x >> 6, lane = threadIdx.x & 63;
  if (lane == 0) {
#pragma unroll
    for (int e = 0; e < NE; ++e) red[wave][e] = acc[e];
  }
  __syncthreads();
  if (threadIdx.x == 0) {
    float l[NE];
#pragma unroll
    for (int e = 0; e < NE; ++e) l[e] = red[0][e] + red[1][e] + red[2][e] + red[3][e];
    int i0 = 0;
#pragma unroll
    for (int e = 1; e < NE; ++e) if (l[e] > l[i0]) i0 = e;
    int i1 = -1;
#pragma unroll
    for (int e = 0; e < NE; ++e) {
      if (e == i0) continue;
      if (i1 < 0 || l[e] > l[i1]) i1 = e;
    }
    float e1 = __expf(l[i1] - l[i0]);
    float w0 = 1.f / (1.f + e1);
    tok_e[t * 2 + 0] = i0;
    tok_e[t * 2 + 1] = i1;
    tok_w[t * 2 + 0] = w0;
    tok_w[t * 2 + 1] = 1.f - w0;
  }
}

// ---------------- routing: per-expert compaction (deterministic, single block) ----------------
__global__ __launch_bounds__(512) void routing_kernel(const int* __restrict__ tok_e,
                                                      int* __restrict__ list_tok,
                                                      int* __restrict__ tok_gslot,
                                                      int* __restrict__ offs_out) {
  __shared__ int cnts[NE];
  __shared__ int offs_s[NE + 1];
  const int e = threadIdx.x >> 6, lane = threadIdx.x & 63;
  int c = 0;
  for (int base = 0; base < NTOK; base += 64) {
    int tok = base + lane;
    int e0 = tok_e[tok * 2], e1 = tok_e[tok * 2 + 1];
    bool m = (e0 == e) || (e1 == e);
    unsigned long long mask = __ballot(m);
    c += __popcll(mask);
  }
  if (lane == 0) cnts[e] = c;
  __syncthreads();
  if (threadIdx.x == 0) {
    int o = 0;
    for (int i = 0; i < NE; ++i) { offs_s[i] = o; o += (cnts[i] + 127) & ~127; }
    offs_s[NE] = o;
    for (int i = 0; i <= NE; ++i) offs_out[i] = offs_s[i];
  }
  __syncthreads();
  const int off = offs_s[e];
  int run = 0;
  for (int base = 0; base < NTOK; base += 64) {
    int tok = base + lane;
    int e0 = tok_e[tok * 2], e1 = tok_e[tok * 2 + 1];
    bool m = (e0 == e) || (e1 == e);
    unsigned long long mask = __ballot(m);
    int pos = run + __popcll(mask & ((1ull << lane) - 1ull));
    if (m) {
      int gs = off + pos;
      list_tok[gs] = tok;
      tok_gslot[tok * 2 + ((e0 == e) ? 0 : 1)] = gs;
    }
    run += __popcll(mask);
  }
  // pad tail slots with token 0 (rows computed but never combined)
  const int cnt = cnts[e];
  const int padded = (cnt + 127) & ~127;
  for (int p = cnt + lane; p < padded; p += 64) list_tok[off + p] = 0;
}

// ---------------- grouped GEMM (m97 structure, 128x128 tile, 4 waves) ----------------
// A: [rows][KTOT] bf16 (FIRST: gathered via list_tok from xb; else direct h rows)
// B: [NE][NTOT][KTOT] bf16 (pre-transposed, K contiguous)
// FIRST: out = bf16 h with bias+GELU; else: out = fp32 o with bias.
template <int KTOT, int NTOT, bool FIRST>
__global__ __launch_bounds__(256) void moe_gemm(const unsigned short* __restrict__ Abase,
                                                const unsigned short* __restrict__ Bbase,
                                                const float* __restrict__ bias,
                                                const int* __restrict__ list_tok,
                                                const int* __restrict__ offs,
                                                void* __restrict__ outp) {
  __shared__ __align__(16) unsigned short lds_a[128 * 32];
  __shared__ __align__(16) unsigned short lds_b[128 * 32];
  const int tid = threadIdx.x;
  const int wave = tid >> 6, lane = tid & 63;
  const int grow0 = blockIdx.y * 128;
  if (grow0 >= offs[NE]) return;
  int e = 0;
#pragma unroll
  for (int i = 1; i < NE; ++i) if (grow0 >= offs[i]) e = i;
  const int n0 = blockIdx.x * 128;

  const int srow = wave * 32 + (lane >> 2);
  const int kc = (lane & 3) * 8;
  size_t arow0, arow1;
  if (FIRST) {
    arow0 = (size_t)list_tok[grow0 + srow] * KTOT;
    arow1 = (size_t)list_tok[grow0 + srow + 16] * KTOT;
  } else {
    arow0 = (size_t)(grow0 + srow) * KTOT;
    arow1 = arow0 + (size_t)16 * KTOT;
  }
  const unsigned short* ag0 = Abase + arow0 + kc;
  const unsigned short* ag1 = Abase + arow1 + kc;
  const unsigned short* Bp = Bbase + (size_t)e * NTOT * KTOT + (size_t)(n0 + srow) * KTOT + kc;
  const unsigned short* bg0 = Bp;
  const unsigned short* bg1 = Bp + (size_t)16 * KTOT;
  unsigned short* lda0 = &lds_a[(wave * 32) * 32];
  unsigned short* lda1 = &lds_a[(wave * 32 + 16) * 32];
  unsigned short* ldb0 = &lds_b[(wave * 32) * 32];
  unsigned short* ldb1 = &lds_b[(wave * 32 + 16) * 32];

  const int wm = wave >> 1, wn = wave & 1;
  const int fr = lane & 15, g8 = (lane >> 4) * 8;

  f32x4 acc[4][4] = {};

  for (int k0 = 0; k0 < KTOT; k0 += 32) {
    gld16(ag0 + k0, lda0);
    gld16(ag1 + k0, lda1);
    gld16(bg0 + k0, ldb0);
    gld16(bg1 + k0, ldb1);
    __syncthreads();
    short8v af[4], bf[4];
#pragma unroll
    for (int m = 0; m < 4; ++m)
      af[m] = *(const short8v*)&lds_a[(wm * 64 + m * 16 + fr) * 32 + g8];
#pragma unroll
    for (int n = 0; n < 4; ++n)
      bf[n] = *(const short8v*)&lds_b[(wn * 64 + n * 16 + fr) * 32 + g8];
#pragma unroll
    for (int m = 0; m < 4; ++m)
#pragma unroll
      for (int n = 0; n < 4; ++n)
        acc[m][n] = __builtin_amdgcn_mfma_f32_16x16x32_bf16(af[m], bf[n], acc[m][n], 0, 0, 0);
    __syncthreads();
  }

  const int r4 = lane >> 4;
#pragma unroll
  for (int m = 0; m < 4; ++m) {
#pragma unroll
    for (int n = 0; n < 4; ++n) {
      const int gcol = n0 + wn * 64 + n * 16 + fr;
      const float bv = bias[e * NTOT + gcol];
#pragma unroll
      for (int r = 0; r < 4; ++r) {
        const int grow = grow0 + wm * 64 + m * 16 + r4 * 4 + r;
        float v = acc[m][n][r] + bv;
        if (FIRST) {
          v = 0.5f * v * (1.0f + erff(v * 0.70710678118654752f));
          ((unsigned short*)outp)[(size_t)grow * NTOT + gcol] = f2bf(v);
        } else {
          ((float*)outp)[(size_t)grow * NTOT + gcol] = v;
        }
      }
    }
  }
}

// ---------------- combine: y[t] = w0*o[gs0] + w1*o[gs1] ----------------
__global__ __launch_bounds__(256) void combine_kernel(const float* __restrict__ o,
                                                      const int* __restrict__ tok_gslot,
                                                      const float* __restrict__ tok_w,
                                                      float* __restrict__ y) {
  const int t = blockIdx.x;
  const int c = threadIdx.x * 4;
  const int gs0 = tok_gslot[t * 2 + 0], gs1 = tok_gslot[t * 2 + 1];
  const float w0 = tok_w[t * 2 + 0], w1 = tok_w[t * 2 + 1];
  f32x4 o0 = *(const f32x4*)&o[(size_t)gs0 * HID + c];
  f32x4 o1 = *(const f32x4*)&o[(size_t)gs1 * HID + c];
  f32x4 r;
#pragma unroll
  for (int i = 0; i < 4; ++i) r[i] = w0 * o0[i] + w1 * o1[i];
  *(f32x4*)&y[(size_t)t * HID + c] = r;
}

extern "C" void kernel_launch(void* const* d_in, const int* in_sizes, int n_in,
                              void* d_out, int out_size, void* d_ws, size_t ws_size,
                              hipStream_t stream) {
  const float* x  = (const float*)d_in[0];
  const float* wg = (const float*)d_in[1];
  const float* W1 = (const float*)d_in[2];
  const float* b1 = (const float*)d_in[3];
  const float* W2 = (const float*)d_in[4];
  const float* b2 = (const float*)d_in[5];
  float* y = (float*)d_out;

  unsigned char* ws = (unsigned char*)d_ws;
  size_t off = 0;
  unsigned short* w1t = (unsigned short*)(ws + off); off += (size_t)NE * INTER * HID * 2;   // 67MB
  unsigned short* w2t = (unsigned short*)(ws + off); off += (size_t)NE * HID * INTER * 2;   // 67MB
  unsigned short* xb  = (unsigned short*)(ws + off); off += (size_t)NTOK * HID * 2;          // 4MB
  unsigned short* h   = (unsigned short*)(ws + off); off += (size_t)MAXROWS * INTER * 2;     // 42MB
  float* ob           = (float*)(ws + off);          off += (size_t)MAXROWS * HID * 4;       // 21MB
  int* tok_e          = (int*)(ws + off);            off += NTOK * 2 * 4;
  float* tok_w        = (float*)(ws + off);          off += NTOK * 2 * 4;
  int* tok_gslot      = (int*)(ws + off);            off += NTOK * 2 * 4;
  int* list_tok       = (int*)(ws + off);            off += MAXROWS * 4;
  int* offs           = (int*)(ws + off);            off += 64;
  (void)ws_size; (void)in_sizes; (void)n_in; (void)out_size;

  convx_kernel<<<(NTOK * HID / 4 + 255) / 256, 256, 0, stream>>>(x, xb);
  tconv_kernel<<<dim3(INTER / 64, HID / 64, NE), 256, 0, stream>>>(W1, w1t, HID, INTER);
  tconv_kernel<<<dim3(HID / 64, INTER / 64, NE), 256, 0, stream>>>(W2, w2t, INTER, HID);
  gating_kernel<<<NTOK, 256, 0, stream>>>(x, wg, tok_e, tok_w);
  routing_kernel<<<1, 512, 0, stream>>>(tok_e, list_tok, tok_gslot, offs);
  moe_gemm<HID, INTER, true><<<dim3(INTER / 128, MAXROWS / 128), 256, 0, stream>>>(
      xb, w1t, b1, list_tok, offs, (void*)h);
  moe_gemm<INTER, HID, false><<<dim3(HID / 128, MAXROWS / 128), 256, 0, stream>>>(
      h, w2t, b2, list_tok, offs, (void*)ob);
  combine_kernel<<<NTOK, 256, 0, stream>>>(ob, tok_gslot, tok_w, y);
}

// Round 2
// 250.868 us; speedup vs baseline: 1.1008x; 1.1008x over previous
//
#include <hip/hip_runtime.h>
#include <hip/hip_bf16.h>

#define HID 1024
#define INTER 4096
#define NE 8
#define NTOK 2048
#define MAXROWS 5120   // 4096 pairs + 8*127 pad, rounded up

typedef __attribute__((ext_vector_type(8))) short short8v;
typedef __attribute__((ext_vector_type(4))) float f32x4;

__device__ __forceinline__ unsigned short f2bf(float f) {
  unsigned int u = __builtin_bit_cast(unsigned int, f);
  u = (u + 0x7FFFu + ((u >> 16) & 1u)) >> 16;
  return (unsigned short)u;
}

typedef const __attribute__((address_space(1))) unsigned int* gas_t;
typedef __attribute__((address_space(3))) unsigned int* las_t;
__device__ __forceinline__ void gld16(const unsigned short* g, unsigned short* l) {
  __builtin_amdgcn_global_load_lds((gas_t)(const void*)g, (las_t)(void*)l, 16, 0, 0);
}

// ---------------- x fp32 -> bf16 (same layout) ----------------
__global__ __launch_bounds__(256) void convx_kernel(const float* __restrict__ in,
                                                    unsigned short* __restrict__ out) {
  size_t i = (size_t)blockIdx.x * 256 + threadIdx.x;
  f32x4 v = *(const f32x4*)&in[i * 4];
  uint2 r;
  r.x = (unsigned int)f2bf(v[0]) | ((unsigned int)f2bf(v[1]) << 16);
  r.y = (unsigned int)f2bf(v[2]) | ((unsigned int)f2bf(v[3]) << 16);
  *(uint2*)&out[i * 4] = r;
}

// ------------- transpose+convert: in [Z][R][C] f32 -> out [Z][C][R] bf16 -------------
__global__ __launch_bounds__(256) void tconv_kernel(const float* __restrict__ in,
                                                    unsigned short* __restrict__ out,
                                                    int R, int C) {
  __shared__ float t[64][65];
  const int z = blockIdx.z;
  const int r0 = blockIdx.y * 64, c0 = blockIdx.x * 64;
  const int tr = threadIdx.x / 16;
  const int tc = (threadIdx.x % 16) * 4;
  const float* ip = in + ((size_t)z * R + r0) * (size_t)C + c0;
#pragma unroll
  for (int p = 0; p < 4; ++p) {
    f32x4 v = *(const f32x4*)&ip[(size_t)(p * 16 + tr) * C + tc];
    t[p * 16 + tr][tc + 0] = v[0];
    t[p * 16 + tr][tc + 1] = v[1];
    t[p * 16 + tr][tc + 2] = v[2];
    t[p * 16 + tr][tc + 3] = v[3];
  }
  __syncthreads();
  unsigned short* op = out + ((size_t)z * C + c0) * (size_t)R + r0;
#pragma unroll
  for (int p = 0; p < 4; ++p) {
    int c = p * 16 + tr;
    unsigned int a0 = (unsigned int)f2bf(t[tc + 0][c]) | ((unsigned int)f2bf(t[tc + 1][c]) << 16);
    unsigned int a1 = (unsigned int)f2bf(t[tc + 2][c]) | ((unsigned int)f2bf(t[tc + 3][c]) << 16);
    uint2 val; val.x = a0; val.y = a1;
    *(uint2*)&op[(size_t)c * R + tc] = val;
  }
}

// ---------------- gating: logits -> top2 + softmax ----------------
__global__ __launch_bounds__(256) void gating_kernel(const float* __restrict__ x,
                                                     const float* __restrict__ wg,
                                                     int* __restrict__ tok_e,
                                                     float* __restrict__ tok_w) {
  const int t = blockIdx.x;
  float acc[NE];
#pragma unroll
  for (int e = 0; e < NE; ++e) acc[e] = 0.f;
  for (int k = threadIdx.x; k < HID; k += 256) {
    float xv = x[(size_t)t * HID + k];
#pragma unroll
    for (int e = 0; e < NE; ++e) acc[e] += xv * wg[e * HID + k];
  }
#pragma unroll
  for (int e = 0; e < NE; ++e) {
#pragma unroll
    for (int off = 32; off >= 1; off >>= 1) acc[e] += __shfl_xor(acc[e], off, 64);
  }
  __shared__ float red[4][NE];
  const int wave = threadIdx.x >> 6, lane = threadIdx.x & 63;
  if (lane == 0) {
#pragma unroll
    for (int e = 0; e < NE; ++e) red[wave][e] = acc[e];
  }
  __syncthreads();
  if (threadIdx.x == 0) {
    float l[NE];
#pragma unroll
    for (int e = 0; e < NE; ++e) l[e] = red[0][e] + red[1][e] + red[2][e] + red[3][e];
    int i0 = 0;
#pragma unroll
    for (int e = 1; e < NE; ++e) if (l[e] > l[i0]) i0 = e;
    int i1 = -1;
#pragma unroll
    for (int e = 0; e < NE; ++e) {
      if (e == i0) continue;
      if (i1 < 0 || l[e] > l[i1]) i1 = e;
    }
    float e1 = __expf(l[i1] - l[i0]);
    float w0 = 1.f / (1.f + e1);
    tok_e[t * 2 + 0] = i0;
    tok_e[t * 2 + 1] = i1;
    tok_w[t * 2 + 0] = w0;
    tok_w[t * 2 + 1] = 1.f - w0;
  }
}

// ---------------- routing: per-expert compaction (deterministic, single block) ----------------
__global__ __launch_bounds__(512) void routing_kernel(const int* __restrict__ tok_e,
                                                      int* __restrict__ list_tok,
                                                      int* __restrict__ tok_gslot,
                                                      int* __restrict__ offs_out) {
  __shared__ int cnts[NE];
  __shared__ int offs_s[NE + 1];
  const int e = threadIdx.x >> 6, lane = threadIdx.x & 63;
  int c = 0;
  for (int base = 0; base < NTOK; base += 64) {
    int tok = base + lane;
    int e0 = tok_e[tok * 2], e1 = tok_e[tok * 2 + 1];
    bool m = (e0 == e) || (e1 == e);
    unsigned long long mask = __ballot(m);
    c += __popcll(mask);
  }
  if (lane == 0) cnts[e] = c;
  __syncthreads();
  if (threadIdx.x == 0) {
    int o = 0;
    for (int i = 0; i < NE; ++i) { offs_s[i] = o; o += (cnts[i] + 127) & ~127; }
    offs_s[NE] = o;
    for (int i = 0; i <= NE; ++i) offs_out[i] = offs_s[i];
  }
  __syncthreads();
  const int off = offs_s[e];
  int run = 0;
  for (int base = 0; base < NTOK; base += 64) {
    int tok = base + lane;
    int e0 = tok_e[tok * 2], e1 = tok_e[tok * 2 + 1];
    bool m = (e0 == e) || (e1 == e);
    unsigned long long mask = __ballot(m);
    int pos = run + __popcll(mask & ((1ull << lane) - 1ull));
    if (m) {
      int gs = off + pos;
      list_tok[gs] = tok;
      tok_gslot[tok * 2 + ((e0 == e) ? 0 : 1)] = gs;
    }
    run += __popcll(mask);
  }
  const int cnt = cnts[e];
  const int padded = (cnt + 127) & ~127;
  for (int p = cnt + lane; p < padded; p += 64) list_tok[off + p] = 0;
}

// ---------------- grouped GEMM: 128x128 tile, BK=64, min-2-phase dbuf + swizzled LDS ----------------
// A: [rows][KTOT] bf16 (FIRST: gathered via list_tok; else direct rows)
// B: [NE][NTOT][KTOT] bf16 (K contiguous)
// FIRST: out = bf16 h with bias+GELU; else: out = fp32 partials[ks][row][col] (no bias).
template <int KTOT, int NTOT, bool FIRST, int NSPLIT>
__global__ __launch_bounds__(256, 2) void moe_gemm(const unsigned short* __restrict__ Abase,
                                                   const unsigned short* __restrict__ Bbase,
                                                   const float* __restrict__ bias,
                                                   const int* __restrict__ list_tok,
                                                   const int* __restrict__ offs,
                                                   void* __restrict__ outp) {
  constexpr int KS = KTOT / NSPLIT;   // K elems per slice
  constexpr int NT = KS / 64;         // K-tiles
  constexpr int nM = MAXROWS / 128;
  constexpr int nN = NTOT / 128;
  __shared__ __align__(16) unsigned short lds[2][2][8192];  // [buf][A/B][128 rows x 64]

  const int nwg = nN * nM * NSPLIT;
  int wg = blockIdx.x;
  wg = (wg & 7) * (nwg >> 3) + (wg >> 3);   // bijective XCD swizzle (nwg % 8 == 0)
  const int ks = (NSPLIT > 1) ? (wg / (nM * nN)) : 0;
  const int rem = wg % (nM * nN);
  const int mt = rem % nM;                  // m fastest: same-expert m-tiles share B panel in L2
  const int nt = rem / nM;
  const int grow0 = mt * 128;
  if (grow0 >= offs[NE]) return;
  int e = 0;
#pragma unroll
  for (int i = 1; i < NE; ++i) if (grow0 >= offs[i]) e = i;
  const int n0 = nt * 128;
  const int k0 = ks * KS;

  const int tid = threadIdx.x;
  const int wave = tid >> 6, lane = tid & 63;

  // --- staging sources (pre-swizzled global col so linear gld16 dest + XOR read works) ---
  const int scol = ((lane & 7) * 8) ^ ((lane >> 3) * 8);  // shorts, within 64-short row
  const unsigned short* ag[4];
  const unsigned short* bg[4];
#pragma unroll
  for (int i = 0; i < 4; ++i) {
    const int row = i * 32 + wave * 8 + (lane >> 3);
    size_t arow;
    if (FIRST) arow = (size_t)list_tok[grow0 + row] * KTOT;
    else       arow = (size_t)(grow0 + row) * KTOT;
    ag[i] = Abase + arow + k0 + scol;
    bg[i] = Bbase + (size_t)e * NTOT * KTOT + (size_t)(n0 + row) * KTOT + k0 + scol;
  }

  // --- fragment read offsets (shorts) ---
  const int wm = wave >> 1, wn = wave & 1;
  const int fr = lane & 15;
  const int kq = (lane >> 4) * 8;
  const int swz = (fr & 7) * 8;
  int aoff[4], boff[4];
#pragma unroll
  for (int m = 0; m < 4; ++m) aoff[m] = (wm * 64 + m * 16 + fr) * 64;
#pragma unroll
  for (int n = 0; n < 4; ++n) boff[n] = (wn * 64 + n * 16 + fr) * 64;
  const int kc0 = (kq) ^ swz;
  const int kc1 = (32 + kq) ^ swz;

  f32x4 acc[4][4] = {};

  // prologue: stage tile 0
#pragma unroll
  for (int i = 0; i < 4; ++i) gld16(ag[i], &lds[0][0][i * 2048 + wave * 512]);
#pragma unroll
  for (int i = 0; i < 4; ++i) gld16(bg[i], &lds[0][1][i * 2048 + wave * 512]);
  __syncthreads();

  for (int t = 0; t < NT; ++t) {
    if (t + 1 < NT) {
      const int bb = (t + 1) & 1;
#pragma unroll
      for (int i = 0; i < 4; ++i) gld16(ag[i] + (t + 1) * 64, &lds[bb][0][i * 2048 + wave * 512]);
#pragma unroll
      for (int i = 0; i < 4; ++i) gld16(bg[i] + (t + 1) * 64, &lds[bb][1][i * 2048 + wave * 512]);
    }
    const unsigned short* A = &lds[t & 1][0][0];
    const unsigned short* B = &lds[t & 1][1][0];
#pragma unroll
    for (int kk = 0; kk < 2; ++kk) {
      const int kc = kk ? kc1 : kc0;
      short8v af[4], bf[4];
#pragma unroll
      for (int m = 0; m < 4; ++m) af[m] = *(const short8v*)&A[aoff[m] + kc];
#pragma unroll
      for (int n = 0; n < 4; ++n) bf[n] = *(const short8v*)&B[boff[n] + kc];
#pragma unroll
      for (int m = 0; m < 4; ++m)
#pragma unroll
        for (int n = 0; n < 4; ++n)
          acc[m][n] = __builtin_amdgcn_mfma_f32_16x16x32_bf16(af[m], bf[n], acc[m][n], 0, 0, 0);
    }
    __syncthreads();  // drains this iter's prefetch (vmcnt 0) + all lds reads
  }

  const int r4 = lane >> 4;
#pragma unroll
  for (int m = 0; m < 4; ++m) {
#pragma unroll
    for (int n = 0; n < 4; ++n) {
      const int gcol = n0 + wn * 64 + n * 16 + fr;
      float bv = 0.f;
      if (FIRST) bv = bias[e * NTOT + gcol];
#pragma unroll
      for (int r = 0; r < 4; ++r) {
        const int grow = grow0 + wm * 64 + m * 16 + r4 * 4 + r;
        float v = acc[m][n][r] + bv;
        if (FIRST) {
          v = 0.5f * v * (1.0f + erff(v * 0.70710678118654752f));
          ((unsigned short*)outp)[(size_t)grow * NTOT + gcol] = f2bf(v);
        } else {
          ((float*)outp)[((size_t)ks * MAXROWS + grow) * NTOT + gcol] = v;
        }
      }
    }
  }
}

// ---------------- combine: y[t] = w0*(sum_ks p[ks][gs0]+b2[e0]) + w1*(...) ----------------
__global__ __launch_bounds__(256) void combine_kernel(const float* __restrict__ part,
                                                      const int* __restrict__ tok_gslot,
                                                      const int* __restrict__ tok_e,
                                                      const float* __restrict__ tok_w,
                                                      const float* __restrict__ b2,
                                                      float* __restrict__ y) {
  const int t = blockIdx.x;
  const int c = threadIdx.x * 4;
  const int gs0 = tok_gslot[t * 2 + 0], gs1 = tok_gslot[t * 2 + 1];
  const int e0 = tok_e[t * 2 + 0], e1 = tok_e[t * 2 + 1];
  const float w0 = tok_w[t * 2 + 0], w1 = tok_w[t * 2 + 1];
  const size_t P1 = (size_t)MAXROWS * HID;
  f32x4 a0 = *(const f32x4*)&part[(size_t)gs0 * HID + c];
  f32x4 a1 = *(const f32x4*)&part[P1 + (size_t)gs0 * HID + c];
  f32x4 d0 = *(const f32x4*)&part[(size_t)gs1 * HID + c];
  f32x4 d1 = *(const f32x4*)&part[P1 + (size_t)gs1 * HID + c];
  f32x4 bb0 = *(const f32x4*)&b2[e0 * HID + c];
  f32x4 bb1 = *(const f32x4*)&b2[e1 * HID + c];
  f32x4 r;
#pragma unroll
  for (int i = 0; i < 4; ++i)
    r[i] = w0 * (a0[i] + a1[i] + bb0[i]) + w1 * (d0[i] + d1[i] + bb1[i]);
  *(f32x4*)&y[(size_t)t * HID + c] = r;
}

extern "C" void kernel_launch(void* const* d_in, const int* in_sizes, int n_in,
                              void* d_out, int out_size, void* d_ws, size_t ws_size,
                              hipStream_t stream) {
  const float* x  = (const float*)d_in[0];
  const float* wg = (const float*)d_in[1];
  const float* W1 = (const float*)d_in[2];
  const float* b1 = (const float*)d_in[3];
  const float* W2 = (const float*)d_in[4];
  const float* b2 = (const float*)d_in[5];
  float* y = (float*)d_out;

  unsigned char* ws = (unsigned char*)d_ws;
  size_t off = 0;
  // w1t (live tconv1->gemm1) aliases partials (live gemm2->combine): 42MB <= 67MB
  unsigned short* w1t = (unsigned short*)(ws + off);
  float* part         = (float*)(ws + off);          off += (size_t)NE * HID * INTER * 2;  // 67MB
  unsigned short* w2t = (unsigned short*)(ws + off); off += (size_t)NE * INTER * HID * 2;  // 67MB
  unsigned short* xb  = (unsigned short*)(ws + off); off += (size_t)NTOK * HID * 2;        // 4MB
  unsigned short* h   = (unsigned short*)(ws + off); off += (size_t)MAXROWS * INTER * 2;   // 42MB
  int* tok_e          = (int*)(ws + off);            off += NTOK * 2 * 4;
  float* tok_w        = (float*)(ws + off);          off += NTOK * 2 * 4;
  int* tok_gslot      = (int*)(ws + off);            off += NTOK * 2 * 4;
  int* list_tok       = (int*)(ws + off);            off += MAXROWS * 4;
  int* offs           = (int*)(ws + off);            off += 64;
  (void)ws_size; (void)in_sizes; (void)n_in; (void)out_size;

  convx_kernel<<<(NTOK * HID / 4 + 255) / 256, 256, 0, stream>>>(x, xb);
  tconv_kernel<<<dim3(INTER / 64, HID / 64, NE), 256, 0, stream>>>(W1, w1t, HID, INTER);
  tconv_kernel<<<dim3(HID / 64, INTER / 64, NE), 256, 0, stream>>>(W2, w2t, INTER, HID);
  gating_kernel<<<NTOK, 256, 0, stream>>>(x, wg, tok_e, tok_w);
  routing_kernel<<<1, 512, 0, stream>>>(tok_e, list_tok, tok_gslot, offs);
  moe_gemm<HID, INTER, true, 1><<<(INTER / 128) * (MAXROWS / 128), 256, 0, stream>>>(
      xb, w1t, b1, list_tok, offs, (void*)h);
  moe_gemm<INTER, HID, false, 2><<<(HID / 128) * (MAXROWS / 128) * 2, 256, 0, stream>>>(
      h, w2t, b2, list_tok, offs, (void*)part);
  combine_kernel<<<NTOK, 256, 0, stream>>>(part, tok_gslot, tok_e, tok_w, b2, y);
}